// Round 21
// baseline (872.994 us; speedup 1.0000x reference)
//
#include <hip/hip_runtime.h>

// GRUModel: B=4096, H=512, V=512, T=31, D_IN=14
// d_out = [probs: 4096*31*512 f32][hidden: 4096*31*512 f32]
#define NTH 15872   // 31*512

typedef __bf16 bf16x8 __attribute__((ext_vector_type(8)));
typedef float  f32x4  __attribute__((ext_vector_type(4)));

__device__ __forceinline__ unsigned short f2bf(float f) {
    unsigned u = __float_as_uint(f);
    u = u + 0x7fffu + ((u >> 16) & 1u);
    return (unsigned short)(u >> 16);
}
__device__ __forceinline__ float sigm(float x)  { return 1.f / (1.f + __expf(-x)); }
__device__ __forceinline__ float tanhf_(float x){ return 2.f / (1.f + __expf(-2.f * x)) - 1.f; }

// Proven LDS tile layout (64B rows, K=32 bf16): chunk ^= (r>>1)&3. (gemm/proj only)
__device__ __forceinline__ int lds_off(int r, int kb) {
    return r * 64 + ((kb ^ ((r >> 1) & 3)) << 4);
}
__device__ __forceinline__ int4 ldg16(const char* g0, int stride, int kbyte, int c) {
    int r = c >> 2, kb = c & 3;
    return *(const int4*)(g0 + (size_t)r * stride + kbyte + kb * 16);
}
__device__ __forceinline__ void sts16(char* lds, int c, int4 v) {
    int r = c >> 2, kb = c & 3;
    *(int4*)(lds + lds_off(r, kb)) = v;
}
__device__ __forceinline__ bf16x8 ldsfrag(const char* lds, int row, int hi) {
    return *(const bf16x8*)(lds + lds_off(row, hi));
}
__device__ __forceinline__ int4 pack8(const float* p) {
    float4 a = ((const float4*)p)[0], b = ((const float4*)p)[1];
    union { unsigned short us[8]; int4 v; } u;
    u.us[0]=f2bf(a.x); u.us[1]=f2bf(a.y); u.us[2]=f2bf(a.z); u.us[3]=f2bf(a.w);
    u.us[4]=f2bf(b.x); u.us[5]=f2bf(b.y); u.us[6]=f2bf(b.z); u.us[7]=f2bf(b.w);
    return u.v;
}
__device__ __forceinline__ int4 ldg16_f32(const float* g0, int stride, int koff, int c) {
    int r = c >> 2, kb = c & 3;
    return pack8(g0 + (size_t)r * stride + koff + kb * 8);
}

// ---------------------------------------------------------------- fused weight prep + linear_in (R19-verbatim)
__global__ __launch_bounds__(256) void k_prep(
    const float* __restrict__ W_ih, const float* __restrict__ W_hh,
    const float* __restrict__ W_out,
    const float* __restrict__ inputs, const float* __restrict__ W_in,
    const float* __restrict__ b_in,
    unsigned short* __restrict__ wih_b,
    unsigned short* __restrict__ Wp,
    unsigned short* __restrict__ wout_b,
    unsigned short* __restrict__ xb) {
    const int bid = blockIdx.x, tid = threadIdx.x;
    if (bid < 768) {
        int i = bid * 256 + tid;
        float4 v = ((const float4*)W_ih)[i];
        ushort4 o; o.x=f2bf(v.x); o.y=f2bf(v.y); o.z=f2bf(v.z); o.w=f2bf(v.w);
        ((ushort4*)wih_b)[i] = o;
    } else if (bid < 1152) {
        int cid = (bid - 768) * 256 + tid;            // [0, 98304)
        int lane = cid & 63, c16 = lane & 15, hi = lane >> 4;
        int wn = (cid >> 6) & 1, nb = (cid >> 7) & 15;
        int v = cid >> 11;                            // kt*3 + g, [0,48)
        int kt = v / 3, g = v - kt * 3;
        int row = g * 512 + nb * 32 + wn * 16 + c16;
        ((int4*)Wp)[cid] = pack8(W_hh + (size_t)row * 512 + kt * 32 + hi * 8);
    } else if (bid < 1408) {
        int i = (bid - 1152) * 256 + tid;
        float4 v = ((const float4*)W_out)[i];
        ushort4 o; o.x=f2bf(v.x); o.y=f2bf(v.y); o.z=f2bf(v.z); o.w=f2bf(v.w);
        ((ushort4*)wout_b)[i] = o;
    } else {
        __shared__ float lW[512 * 14];
        __shared__ float lI[8 * 14];
        const int r0 = (bid - 1408) * 8;
#pragma unroll
        for (int i = 0; i < 28; ++i) lW[i * 256 + tid] = W_in[i * 256 + tid];
        if (tid < 112) lI[tid] = inputs[r0 * 14 + tid];
        __syncthreads();
#pragma unroll
        for (int i = 0; i < 16; ++i) {
            int idx = i * 256 + tid, r = idx >> 9, j = idx & 511;
            float acc = b_in[j];
            const float* wr = lW + j * 14;
            const float* ir = lI + r * 14;
#pragma unroll
            for (int k = 0; k < 14; ++k) acc += ir[k] * wr[k];
            xb[(size_t)(r0 + r) * 512 + j] = f2bf(acc);
        }
    }
}

// ---------------------------------------------------------------- gi = x @ W_ih.T + b_ih (R1-verbatim)
__global__ __launch_bounds__(256) void k_gemm_gi(
    const unsigned short* __restrict__ A,   // [4096,512] bf16
    const unsigned short* __restrict__ W,   // [1536,512] bf16
    const float* __restrict__ bias,         // [1536]
    float* __restrict__ C)                  // [4096,1536]
{
    __shared__ __align__(16) char lA[128 * 64];
    __shared__ __align__(16) char lB[64 * 64];
    const int tid = threadIdx.x, lane = tid & 63, wid = tid >> 6;
    const int wm = wid >> 1, wn = wid & 1, hi = lane >> 4, c16 = lane & 15;
    const int m0 = blockIdx.x * 128, n0 = blockIdx.y * 64;
    const char* ga = (const char*)(A + (size_t)m0 * 512);
    const char* gb = (const char*)(W + (size_t)n0 * 512);
    f32x4 acc[4][2] = {};
    int4 ra0 = ldg16(ga, 1024, 0, tid);
    int4 ra1 = ldg16(ga, 1024, 0, tid + 256);
    int4 rb0 = ldg16(gb, 1024, 0, tid);
    for (int kt = 0; kt < 16; ++kt) {
        if (kt) __syncthreads();
        sts16(lA, tid, ra0); sts16(lA, tid + 256, ra1); sts16(lB, tid, rb0);
        __syncthreads();
        if (kt < 15) {
            int kb = (kt + 1) * 64;
            ra0 = ldg16(ga, 1024, kb, tid);
            ra1 = ldg16(ga, 1024, kb, tid + 256);
            rb0 = ldg16(gb, 1024, kb, tid);
        }
        bf16x8 af[4];
#pragma unroll
        for (int i = 0; i < 4; ++i) af[i] = ldsfrag(lA, wm * 64 + i * 16 + c16, hi);
#pragma unroll
        for (int j = 0; j < 2; ++j) {
            bf16x8 bfr = ldsfrag(lB, wn * 32 + j * 16 + c16, hi);
#pragma unroll
            for (int i = 0; i < 4; ++i)
                acc[i][j] = __builtin_amdgcn_mfma_f32_16x16x32_bf16(af[i], bfr, acc[i][j], 0, 0, 0);
        }
    }
#pragma unroll
    for (int i = 0; i < 4; ++i) {
        int m = m0 + wm * 64 + i * 16 + hi * 4;
#pragma unroll
        for (int j = 0; j < 2; ++j) {
            int n = n0 + wn * 32 + j * 16 + c16;
            float bj = bias[n];
#pragma unroll
            for (int q = 0; q < 4; ++q)
                C[(size_t)(m + q) * 1536 + n] = acc[i][j][q] + bj;
        }
    }
}

// ---------------------------------------------------------------- fused GRU step v12 — ZERO LDS, ZERO BARRIERS
// BM=64, BN=64/gate (grid 64x8 -> 2 blocks/CU), 4 wn-split waves, wave tile
// 64 rows x 16 cols/gate (12 MFMA/kt, R16-identical). BOTH operands come
// fragment-packed from global:
//   B: Wp (R13)  — 3 coalesced 1KB wave loads per kt
//   A: hP        — 4 coalesced 1KB wave loads per kt; hP is written by the
//      PREVIOUS step's epilogue in MFMA-A-fragment order:
//      chunk(rb=m>>4, kt=n>>5) at ushort (oct*128 + (m&15)*8 + e) holds
//      h[rb*16+(m&15)][kt*32+oct*8+e]   (oct=(n>>3)&3, e=n&7)
// Same fragment contents & MFMA order as R16 -> bitwise-identical trajectory.
// No __syncthreads in the K-loop: pure load->MFMA stream, compiler-pipelined.
__global__ __launch_bounds__(256) void k_step(
    const unsigned short* __restrict__ hPin,  // packed h^(t-1), 4 MB
    const unsigned short* __restrict__ Wp,    // packed W_hh fragments
    const float* __restrict__ gi,             // [4096,1536]
    const float* __restrict__ bhh,            // [1536]
    float* __restrict__ hidden,               // [4096, 15872] f32 (d_out region)
    unsigned short* __restrict__ hPout,       // packed h^t, 4 MB
    int t)
{
    const int tid = threadIdx.x, lane = tid & 63, wn = tid >> 6;
    const int hi = lane >> 4, c16 = lane & 15;
    const int bx = blockIdx.x, m0 = bx * 64;
    const int strip = blockIdx.y * 4 + wn;          // 16-col strip in [0,32)
    f32x4 acc[3][4] = {};
    if (t > 0) {
        // A: chunk (bx*4+i)*16 + kt ; byte = chunk*1024 + lane*16
        const char* pa = (const char*)hPin + (size_t)bx * 65536 + lane * 16;
        const char* wp = (const char*)Wp + (size_t)strip * 1024 + lane * 16;
        bf16x8 Af[2][4], Bf[2][3];
#pragma unroll
        for (int i = 0; i < 4; ++i) Af[0][i] = *(const bf16x8*)(pa + i * 16384);
#pragma unroll
        for (int g = 0; g < 3; ++g) Bf[0][g] = *(const bf16x8*)(wp + (size_t)g * 32768);
#pragma unroll
        for (int kt = 0; kt < 16; ++kt) {
            const int cur = kt & 1;
            if (kt < 15) {
#pragma unroll
                for (int i = 0; i < 4; ++i)
                    Af[cur ^ 1][i] = *(const bf16x8*)(pa + i * 16384 + (kt + 1) * 1024);
#pragma unroll
                for (int g = 0; g < 3; ++g)
                    Bf[cur ^ 1][g] = *(const bf16x8*)(wp + (size_t)((kt + 1) * 3 + g) * 32768);
            }
#pragma unroll
            for (int g = 0; g < 3; ++g) {
#pragma unroll
                for (int i = 0; i < 4; ++i)
                    acc[g][i] = __builtin_amdgcn_mfma_f32_16x16x32_bf16(Af[cur][i], Bf[cur][g], acc[g][i], 0, 0, 0);
            }
        }
    }
    // epilogue: gate math (16 outputs/thread); h^t written fragment-packed
    const int n = strip * 16 + c16;                 // gate-local column
    const int ktn = n >> 5, oct = (n >> 3) & 3, e = n & 7;
    const float br = bhh[n], bz = bhh[512 + n], bn_ = bhh[1024 + n];
#pragma unroll
    for (int i = 0; i < 4; ++i) {
        const int rb = bx * 4 + i;
        // ushort offset within chunk: oct*128 + (m&15)*8 + e  (FIX: oct<<7)
        unsigned short* hc = hPout + ((size_t)(rb * 16 + ktn) << 9) + (oct << 7) + e;
#pragma unroll
        for (int q = 0; q < 4; ++q) {
            int m = m0 + i * 16 + hi * 4 + q;
            size_t gb0 = (size_t)m * 1536 + n;
            float pr = gi[gb0]        + acc[0][i][q] + br;
            float pz = gi[gb0 + 512]  + acc[1][i][q] + bz;
            float r  = sigm(pr);
            float z  = sigm(pz);
            float nn = tanhf_(gi[gb0 + 1024] + r * (acc[2][i][q] + bn_));
            float hold = (t > 0) ? hidden[(size_t)m * NTH + (size_t)(t - 1) * 512 + n] : 0.f;
            float hn = (1.f - z) * nn + z * hold;
            hidden[(size_t)m * NTH + (size_t)t * 512 + n] = hn;
            hc[(size_t)(hi * 4 + q) * 8] = f2bf(hn);   // row (m&15) stride 8 ushorts
        }
    }
}

// ---------------------------------------------------------------- projection + softmax (R4-verbatim, f32 A)
template<bool BF16A>
__global__ __launch_bounds__(256) void k_proj(
    const void* __restrict__ Aptr, int astr,
    const unsigned short* __restrict__ Wo,
    const float* __restrict__ bo,
    float* __restrict__ out)
{
    __shared__ __align__(16) char lA[64 * 64];
    __shared__ __align__(16) char lB[512 * 64];
    __shared__ float red[2][2][32];
    const int tid = threadIdx.x, lane = tid & 63, wid = tid >> 6;
    const int wm = wid >> 1, wn = wid & 1, hi = lane >> 4, c16 = lane & 15;
    const int m0 = blockIdx.x * 64;
    const char*  gab = (const char*)Aptr  + (size_t)m0 * astr * 2;
    const float* gaf = (const float*)Aptr + (size_t)m0 * astr;
    const char*  gb  = (const char*)Wo;
    f32x4 acc[2][16] = {};
    int4 ra = BF16A ? ldg16(gab, astr * 2, 0, tid) : ldg16_f32(gaf, astr, 0, tid);
    int4 rb[8];
#pragma unroll
    for (int s = 0; s < 8; ++s) rb[s] = ldg16(gb, 1024, 0, tid + 256 * s);
    for (int kt = 0; kt < 16; ++kt) {
        if (kt) __syncthreads();
        sts16(lA, tid, ra);
#pragma unroll
        for (int s = 0; s < 8; ++s) sts16(lB, tid + 256 * s, rb[s]);
        __syncthreads();
        if (kt < 15) {
            ra = BF16A ? ldg16(gab, astr * 2, (kt + 1) * 64, tid)
                       : ldg16_f32(gaf, astr, (kt + 1) * 32, tid);
#pragma unroll
            for (int s = 0; s < 8; ++s) rb[s] = ldg16(gb, 1024, (kt + 1) * 64, tid + 256 * s);
        }
        bf16x8 af[2];
#pragma unroll
        for (int mf = 0; mf < 2; ++mf)
            af[mf] = ldsfrag(lA, wm * 32 + mf * 16 + c16, hi);
#pragma unroll
        for (int nf = 0; nf < 16; ++nf) {
            bf16x8 bfr = ldsfrag(lB, wn * 256 + nf * 16 + c16, hi);
#pragma unroll
            for (int mf = 0; mf < 2; ++mf)
                acc[mf][nf] = __builtin_amdgcn_mfma_f32_16x16x32_bf16(af[mf], bfr, acc[mf][nf], 0, 0, 0);
        }
    }
#pragma unroll
    for (int nf = 0; nf < 16; ++nf) {
        float bj = bo[wn * 256 + nf * 16 + c16];
#pragma unroll
        for (int mf = 0; mf < 2; ++mf)
#pragma unroll
            for (int q = 0; q < 4; ++q)
                acc[mf][nf][q] = __expf(acc[mf][nf][q] + bj);
    }
#pragma unroll
    for (int mf = 0; mf < 2; ++mf)
#pragma unroll
        for (int q = 0; q < 4; ++q) {
            float s = 0.f;
#pragma unroll
            for (int nf = 0; nf < 16; ++nf) s += acc[mf][nf][q];
            s += __shfl_xor(s, 1); s += __shfl_xor(s, 2);
            s += __shfl_xor(s, 4); s += __shfl_xor(s, 8);
            if (c16 == 0) red[wm][wn][mf * 16 + hi * 4 + q] = s;
        }
    __syncthreads();
#pragma unroll
    for (int mf = 0; mf < 2; ++mf)
#pragma unroll
        for (int q = 0; q < 4; ++q) {
            int rl = mf * 16 + hi * 4 + q;
            float inv = 1.f / (red[wm][0][rl] + red[wm][1][rl]);
            int m = m0 + wm * 32 + rl;
            float* orow = out + (size_t)m * 512 + wn * 256 + c16;
#pragma unroll
            for (int nf = 0; nf < 16; ++nf) orow[nf * 16] = acc[mf][nf][q] * inv;
        }
}

// ---------------------------------------------------------------- launch
extern "C" void kernel_launch(void* const* d_in, const int* in_sizes, int n_in,
                              void* d_out, int out_size, void* d_ws, size_t ws_size,
                              hipStream_t stream) {
    const float* inputs = (const float*)d_in[0];
    const float* W_in   = (const float*)d_in[1];
    const float* b_in   = (const float*)d_in[2];
    const float* W_ih   = (const float*)d_in[3];
    const float* b_ih   = (const float*)d_in[4];
    const float* W_hh   = (const float*)d_in[5];
    const float* b_hh   = (const float*)d_in[6];
    const float* W_out  = (const float*)d_in[7];
    const float* b_out  = (const float*)d_in[8];

    float* out    = (float*)d_out;
    float* hidden = out + (size_t)126976 * 512;

    char* ws = (char*)d_ws;
    unsigned short* wih_b  = (unsigned short*)(ws);                 // 1.5 MB
    unsigned short* Wp     = (unsigned short*)(ws + 1572864);       // 1.5 MB packed W_hh
    unsigned short* wout_b = (unsigned short*)(ws + 3145728);       // 0.5 MB
    unsigned short* x_b    = (unsigned short*)(ws + 3670016);       // 4 MB
    float*          gi     = (float*)(ws + 7864320);                // 25.2 MB
    unsigned short* hP0    = (unsigned short*)(ws + 33030144);      // 4 MB packed h ping
    unsigned short* hP1    = (unsigned short*)(ws + 37224448);      // 4 MB packed h pong

    k_prep<<<1920, 256, 0, stream>>>(W_ih, W_hh, W_out, inputs, W_in, b_in,
                                     wih_b, Wp, wout_b, x_b);
    k_gemm_gi<<<dim3(32, 24), 256, 0, stream>>>(x_b, wih_b, b_ih, gi);

    for (int t = 0; t < 31; ++t) {
        const unsigned short* hin = (t & 1) ? hP0 : hP1;   // t=0: unused
        unsigned short*       hout = (t & 1) ? hP1 : hP0;
        k_step<<<dim3(64, 8), 256, 0, stream>>>(hin, Wp, gi, b_hh,
                                                hidden, hout, t);
    }
    k_proj<false><<<1984, 256, 0, stream>>>(hidden, 512, wout_b, b_out, out);
}

// Round 22
// 727.938 us; speedup vs baseline: 1.1993x; 1.1993x over previous
//
#include <hip/hip_runtime.h>

// GRUModel: B=4096, H=512, V=512, T=31, D_IN=14
// d_out = [probs: 4096*31*512 f32][hidden: 4096*31*512 f32]
#define NTH 15872   // 31*512

typedef __bf16 bf16x8 __attribute__((ext_vector_type(8)));
typedef float  f32x4  __attribute__((ext_vector_type(4)));

__device__ __forceinline__ unsigned short f2bf(float f) {
    unsigned u = __float_as_uint(f);
    u = u + 0x7fffu + ((u >> 16) & 1u);
    return (unsigned short)(u >> 16);
}
__device__ __forceinline__ float sigm(float x)  { return 1.f / (1.f + __expf(-x)); }
__device__ __forceinline__ float tanhf_(float x){ return 2.f / (1.f + __expf(-2.f * x)) - 1.f; }

// Proven LDS tile layout (64B rows, K=32 bf16): chunk ^= (r>>1)&3.
__device__ __forceinline__ int lds_off(int r, int kb) {
    return r * 64 + ((kb ^ ((r >> 1) & 3)) << 4);
}
__device__ __forceinline__ int4 ldg16(const char* g0, int stride, int kbyte, int c) {
    int r = c >> 2, kb = c & 3;
    return *(const int4*)(g0 + (size_t)r * stride + kbyte + kb * 16);
}
__device__ __forceinline__ void sts16(char* lds, int c, int4 v) {
    int r = c >> 2, kb = c & 3;
    *(int4*)(lds + lds_off(r, kb)) = v;
}
__device__ __forceinline__ bf16x8 ldsfrag(const char* lds, int row, int hi) {
    return *(const bf16x8*)(lds + lds_off(row, hi));
}
__device__ __forceinline__ int4 pack8(const float* p) {
    float4 a = ((const float4*)p)[0], b = ((const float4*)p)[1];
    union { unsigned short us[8]; int4 v; } u;
    u.us[0]=f2bf(a.x); u.us[1]=f2bf(a.y); u.us[2]=f2bf(a.z); u.us[3]=f2bf(a.w);
    u.us[4]=f2bf(b.x); u.us[5]=f2bf(b.y); u.us[6]=f2bf(b.z); u.us[7]=f2bf(b.w);
    return u.v;
}
__device__ __forceinline__ int4 ldg16_f32(const float* g0, int stride, int koff, int c) {
    int r = c >> 2, kb = c & 3;
    return pack8(g0 + (size_t)r * stride + koff + kb * 8);
}

// ---------------------------------------------------------------- fused weight prep
__global__ void k_prep(const float* __restrict__ W_ih, const float* __restrict__ W_hh,
                       const float* __restrict__ W_out,
                       unsigned short* __restrict__ wih_b,
                       unsigned short* __restrict__ Wp,
                       unsigned short* __restrict__ wout_b) {
    const int bid = blockIdx.x, tid = threadIdx.x;
    if (bid < 768) {
        int i = bid * 256 + tid;
        float4 v = ((const float4*)W_ih)[i];
        ushort4 o; o.x=f2bf(v.x); o.y=f2bf(v.y); o.z=f2bf(v.z); o.w=f2bf(v.w);
        ((ushort4*)wih_b)[i] = o;
    } else if (bid < 1152) {
        int cid = (bid - 768) * 256 + tid;            // [0, 98304)
        int lane = cid & 63, c16 = lane & 15, hi = lane >> 4;
        int wn = (cid >> 6) & 1, nb = (cid >> 7) & 15;
        int v = cid >> 11;                            // kt*3 + g, [0,48)
        int kt = v / 3, g = v - kt * 3;
        int row = g * 512 + nb * 32 + wn * 16 + c16;
        ((int4*)Wp)[cid] = pack8(W_hh + (size_t)row * 512 + kt * 32 + hi * 8);
    } else {
        int i = (bid - 1152) * 256 + tid;
        float4 v = ((const float4*)W_out)[i];
        ushort4 o; o.x=f2bf(v.x); o.y=f2bf(v.y); o.z=f2bf(v.z); o.w=f2bf(v.w);
        ((ushort4*)wout_b)[i] = o;
    }
}

// ---------------------------------------------------------------- x = inputs @ W_in.T + b_in -> bf16
__global__ __launch_bounds__(256) void k_linear_in(
    const float* __restrict__ inp,   // [4096,14]
    const float* __restrict__ W,     // [512,14]
    const float* __restrict__ bias,  // [512]
    unsigned short* __restrict__ xb) // [4096,512] bf16
{
    __shared__ float lW[512 * 14];
    __shared__ float lI[8 * 14];
    const int tid = threadIdx.x, r0 = blockIdx.x * 8;
#pragma unroll
    for (int i = 0; i < 28; ++i) lW[i * 256 + tid] = W[i * 256 + tid];
    if (tid < 112) lI[tid] = inp[r0 * 14 + tid];
    __syncthreads();
#pragma unroll
    for (int i = 0; i < 16; ++i) {
        int idx = i * 256 + tid, r = idx >> 9, j = idx & 511;
        float acc = bias[j];
        const float* wr = lW + j * 14;
        const float* ir = lI + r * 14;
#pragma unroll
        for (int k = 0; k < 14; ++k) acc += ir[k] * wr[k];
        xb[(size_t)(r0 + r) * 512 + j] = f2bf(acc);
    }
}

// ---------------------------------------------------------------- gi = x @ W_ih.T + b_ih (R1-verbatim)
__global__ __launch_bounds__(256) void k_gemm_gi(
    const unsigned short* __restrict__ A,   // [4096,512] bf16
    const unsigned short* __restrict__ W,   // [1536,512] bf16
    const float* __restrict__ bias,         // [1536]
    float* __restrict__ C)                  // [4096,1536]
{
    __shared__ __align__(16) char lA[128 * 64];
    __shared__ __align__(16) char lB[64 * 64];
    const int tid = threadIdx.x, lane = tid & 63, wid = tid >> 6;
    const int wm = wid >> 1, wn = wid & 1, hi = lane >> 4, c16 = lane & 15;
    const int m0 = blockIdx.x * 128, n0 = blockIdx.y * 64;
    const char* ga = (const char*)(A + (size_t)m0 * 512);
    const char* gb = (const char*)(W + (size_t)n0 * 512);
    f32x4 acc[4][2] = {};
    int4 ra0 = ldg16(ga, 1024, 0, tid);
    int4 ra1 = ldg16(ga, 1024, 0, tid + 256);
    int4 rb0 = ldg16(gb, 1024, 0, tid);
    for (int kt = 0; kt < 16; ++kt) {
        if (kt) __syncthreads();
        sts16(lA, tid, ra0); sts16(lA, tid + 256, ra1); sts16(lB, tid, rb0);
        __syncthreads();
        if (kt < 15) {
            int kb = (kt + 1) * 64;
            ra0 = ldg16(ga, 1024, kb, tid);
            ra1 = ldg16(ga, 1024, kb, tid + 256);
            rb0 = ldg16(gb, 1024, kb, tid);
        }
        bf16x8 af[4];
#pragma unroll
        for (int i = 0; i < 4; ++i) af[i] = ldsfrag(lA, wm * 64 + i * 16 + c16, hi);
#pragma unroll
        for (int j = 0; j < 2; ++j) {
            bf16x8 bfr = ldsfrag(lB, wn * 32 + j * 16 + c16, hi);
#pragma unroll
            for (int i = 0; i < 4; ++i)
                acc[i][j] = __builtin_amdgcn_mfma_f32_16x16x32_bf16(af[i], bfr, acc[i][j], 0, 0, 0);
        }
    }
#pragma unroll
    for (int i = 0; i < 4; ++i) {
        int m = m0 + wm * 64 + i * 16 + hi * 4;
#pragma unroll
        for (int j = 0; j < 2; ++j) {
            int n = n0 + wn * 32 + j * 16 + c16;
            float bj = bias[n];
#pragma unroll
            for (int q = 0; q < 4; ++q)
                C[(size_t)(m + q) * 1536 + n] = acc[i][j][q] + bj;
        }
    }
}

// ---------------------------------------------------------------- fused GRU step (R16-verbatim, best measured)
// BM=64, BN=64/gate (grid 64x8 -> 2 blocks/CU), BK=32, 4 wn-split waves,
// wave tile 64 rows x 16 cols/gate, lds_off A-dbuf single-barrier,
// B fragment-direct from Wp (one coalesced 1KB load per (kt,g) per wave).
__global__ __launch_bounds__(256) void k_step(
    const unsigned short* __restrict__ Hin, int hstride,  // elems
    const unsigned short* __restrict__ Wp,    // packed W_hh fragments
    const float* __restrict__ gi,             // [4096,1536]
    const float* __restrict__ bhh,            // [1536]
    float* __restrict__ hidden,               // [4096, 15872] f32 (d_out region)
    unsigned short* __restrict__ Hout, int ostride,       // elems
    int t)
{
    __shared__ __align__(16) char lA[2][64 * 64];   // 2 x 4 KB
    const int tid = threadIdx.x, lane = tid & 63, wn = tid >> 6;
    const int hi = lane >> 4, c16 = lane & 15;
    const int m0 = blockIdx.x * 64;
    f32x4 acc[3][4] = {};
    if (t > 0) {
        const char* ga = (const char*)(Hin + (size_t)m0 * hstride);
        const int gas = hstride * 2;              // row stride bytes
        const char* wp = (const char*)Wp + (size_t)(blockIdx.y * 4 + wn) * 1024 + lane * 16;
        int4 ra0 = ldg16(ga, gas, 0, tid);        // A: 64 rows x 4 chunks = 1/thread
        bf16x8 Bf[2][3];
#pragma unroll
        for (int g = 0; g < 3; ++g)
            Bf[0][g] = *(const bf16x8*)(wp + (size_t)g * 32768);
        sts16(lA[0], tid, ra0);
        for (int kt = 0; kt < 16; ++kt) {
            const int cur = kt & 1;
            if (kt < 15) {
                int kb = (kt + 1) * 64;
                ra0 = ldg16(ga, gas, kb, tid);
#pragma unroll
                for (int g = 0; g < 3; ++g)
                    Bf[(kt + 1) & 1][g] =
                        *(const bf16x8*)(wp + (size_t)((kt + 1) * 3 + g) * 32768);
            }
            __syncthreads();   // publishes lA[cur] (written pre-loop or in kt-1)
            bf16x8 af[4];
#pragma unroll
            for (int i = 0; i < 4; ++i) af[i] = ldsfrag(lA[cur], i * 16 + c16, hi);
#pragma unroll
            for (int g = 0; g < 3; ++g) {
#pragma unroll
                for (int i = 0; i < 4; ++i)
                    acc[g][i] = __builtin_amdgcn_mfma_f32_16x16x32_bf16(af[i], Bf[cur][g], acc[g][i], 0, 0, 0);
            }
            if (kt < 15) sts16(lA[cur ^ 1], tid, ra0);
        }
    }
    // epilogue: gate math (16 outputs/thread, r/z/n wave-local)
    const int n = blockIdx.y * 64 + wn * 16 + c16;  // gate-local column
    const float br = bhh[n], bz = bhh[512 + n], bn_ = bhh[1024 + n];
#pragma unroll
    for (int i = 0; i < 4; ++i) {
        int mB = m0 + i * 16 + hi * 4;
#pragma unroll
        for (int q = 0; q < 4; ++q) {
            int m = mB + q;
            size_t gb0 = (size_t)m * 1536 + n;
            float pr = gi[gb0]        + acc[0][i][q] + br;
            float pz = gi[gb0 + 512]  + acc[1][i][q] + bz;
            float r  = sigm(pr);
            float z  = sigm(pz);
            float nn = tanhf_(gi[gb0 + 1024] + r * (acc[2][i][q] + bn_));
            float hold = (t > 0) ? hidden[(size_t)m * NTH + (size_t)(t - 1) * 512 + n] : 0.f;
            float hn = (1.f - z) * nn + z * hold;
            hidden[(size_t)m * NTH + (size_t)t * 512 + n] = hn;
            Hout[(size_t)m * ostride + n] = f2bf(hn);
        }
    }
}

// ---------------------------------------------------------------- projection + softmax (R4-verbatim)
// BM=64, BN=512 (full V), BK=32, 256 thr = 4 waves in 2x2; wave tile 32x256.
template<bool BF16A>
__global__ __launch_bounds__(256) void k_proj(
    const void* __restrict__ Aptr,          // bf16 or f32 [126976,512], row stride astr elems
    int astr,
    const unsigned short* __restrict__ Wo,  // [512,512] bf16
    const float* __restrict__ bo,
    float* __restrict__ out)                // [126976,512]
{
    __shared__ __align__(16) char lA[64 * 64];
    __shared__ __align__(16) char lB[512 * 64];
    __shared__ float red[2][2][32];
    const int tid = threadIdx.x, lane = tid & 63, wid = tid >> 6;
    const int wm = wid >> 1, wn = wid & 1, hi = lane >> 4, c16 = lane & 15;
    const int m0 = blockIdx.x * 64;
    const char*  gab = (const char*)Aptr  + (size_t)m0 * astr * 2;
    const float* gaf = (const float*)Aptr + (size_t)m0 * astr;
    const char*  gb  = (const char*)Wo;
    f32x4 acc[2][16] = {};
    int4 ra = BF16A ? ldg16(gab, astr * 2, 0, tid) : ldg16_f32(gaf, astr, 0, tid);
    int4 rb[8];
#pragma unroll
    for (int s = 0; s < 8; ++s) rb[s] = ldg16(gb, 1024, 0, tid + 256 * s);
    for (int kt = 0; kt < 16; ++kt) {
        if (kt) __syncthreads();
        sts16(lA, tid, ra);
#pragma unroll
        for (int s = 0; s < 8; ++s) sts16(lB, tid + 256 * s, rb[s]);
        __syncthreads();
        if (kt < 15) {
            ra = BF16A ? ldg16(gab, astr * 2, (kt + 1) * 64, tid)
                       : ldg16_f32(gaf, astr, (kt + 1) * 32, tid);
#pragma unroll
            for (int s = 0; s < 8; ++s) rb[s] = ldg16(gb, 1024, (kt + 1) * 64, tid + 256 * s);
        }
        bf16x8 af[2];
#pragma unroll
        for (int mf = 0; mf < 2; ++mf)
            af[mf] = ldsfrag(lA, wm * 32 + mf * 16 + c16, hi);
#pragma unroll
        for (int nf = 0; nf < 16; ++nf) {
            bf16x8 bfr = ldsfrag(lB, wn * 256 + nf * 16 + c16, hi);
#pragma unroll
            for (int mf = 0; mf < 2; ++mf)
                acc[mf][nf] = __builtin_amdgcn_mfma_f32_16x16x32_bf16(af[mf], bfr, acc[mf][nf], 0, 0, 0);
        }
    }
#pragma unroll
    for (int nf = 0; nf < 16; ++nf) {
        float bj = bo[wn * 256 + nf * 16 + c16];
#pragma unroll
        for (int mf = 0; mf < 2; ++mf)
#pragma unroll
            for (int q = 0; q < 4; ++q)
                acc[mf][nf][q] = __expf(acc[mf][nf][q] + bj);
    }
#pragma unroll
    for (int mf = 0; mf < 2; ++mf)
#pragma unroll
        for (int q = 0; q < 4; ++q) {
            float s = 0.f;
#pragma unroll
            for (int nf = 0; nf < 16; ++nf) s += acc[mf][nf][q];
            s += __shfl_xor(s, 1); s += __shfl_xor(s, 2);
            s += __shfl_xor(s, 4); s += __shfl_xor(s, 8);
            if (c16 == 0) red[wm][wn][mf * 16 + hi * 4 + q] = s;
        }
    __syncthreads();
#pragma unroll
    for (int mf = 0; mf < 2; ++mf)
#pragma unroll
        for (int q = 0; q < 4; ++q) {
            int rl = mf * 16 + hi * 4 + q;
            float inv = 1.f / (red[wm][0][rl] + red[wm][1][rl]);
            int m = m0 + wm * 32 + rl;
            float* orow = out + (size_t)m * 512 + wn * 256 + c16;
#pragma unroll
            for (int nf = 0; nf < 16; ++nf) orow[nf * 16] = acc[mf][nf][q] * inv;
        }
}

// ---------------------------------------------------------------- launch
extern "C" void kernel_launch(void* const* d_in, const int* in_sizes, int n_in,
                              void* d_out, int out_size, void* d_ws, size_t ws_size,
                              hipStream_t stream) {
    const float* inputs = (const float*)d_in[0];
    const float* W_in   = (const float*)d_in[1];
    const float* b_in   = (const float*)d_in[2];
    const float* W_ih   = (const float*)d_in[3];
    const float* b_ih   = (const float*)d_in[4];
    const float* W_hh   = (const float*)d_in[5];
    const float* b_hh   = (const float*)d_in[6];
    const float* W_out  = (const float*)d_in[7];
    const float* b_out  = (const float*)d_in[8];

    float* out    = (float*)d_out;
    float* hidden = out + (size_t)126976 * 512;

    char* ws = (char*)d_ws;
    unsigned short* wih_b  = (unsigned short*)(ws);                 // 1.5 MB
    unsigned short* Wp     = (unsigned short*)(ws + 1572864);       // 1.5 MB packed W_hh
    unsigned short* wout_b = (unsigned short*)(ws + 3145728);       // 0.5 MB
    unsigned short* x_b    = (unsigned short*)(ws + 3670016);       // 4 MB
    float*          gi     = (float*)(ws + 7864320);                // 25.2 MB
    const bool big = ws_size >= 163053568ULL;                       // hbf2 slab fits?
    unsigned short* hbf2   = (unsigned short*)(ws + 33030144);      // big: [126976,512] bf16
    unsigned short* hb0    = (unsigned short*)(ws + 33030144);      // small: ping-pong
    unsigned short* hb1    = (unsigned short*)(ws + 37224448);

    k_prep<<<1408, 256, 0, stream>>>(W_ih, W_hh, W_out, wih_b, Wp, wout_b);
    k_linear_in<<<512, 256, 0, stream>>>(inputs, W_in, b_in, x_b);
    k_gemm_gi<<<dim3(32, 24), 256, 0, stream>>>(x_b, wih_b, b_ih, gi);

    for (int t = 0; t < 31; ++t) {
        const unsigned short* Hin;
        unsigned short* Hout;
        int hs, os;
        if (big) {
            Hin  = hbf2 + (size_t)(t > 0 ? t - 1 : 0) * 512;  hs = NTH;
            Hout = hbf2 + (size_t)t * 512;                     os = NTH;
        } else {
            Hin  = (t & 1) ? hb0 : hb1;  hs = 512;
            Hout = (t & 1) ? hb1 : hb0;  os = 512;
        }
        k_step<<<dim3(64, 8), 256, 0, stream>>>(Hin, hs, Wp, gi, b_hh,
                                                hidden, Hout, os, t);
    }
    // hbf2 viewed as [126976,512] row-major has row stride 512
    if (big) k_proj<true><<<1984, 256, 0, stream>>>(hbf2, 512, wout_b, b_out, out);
    else     k_proj<false><<<1984, 256, 0, stream>>>(hidden, 512, wout_b, b_out, out);
}